// Round 11
// baseline (1078.519 us; speedup 1.0000x reference)
//
#include <hip/hip_runtime.h>
#include <math.h>

#define NCLU 196
#define DIM  256
#define DV4  (DIM / 4)
#define TEMPERATURE 0.5f
#define EPSV 1e-12f
#define TPB  256
#define SLICES 8          // dim slices of 32
#define DPS    32         // dims per slice
#define LDP    33         // padded LDS row (+1 float -> label enters bank index)
#define MAXCH  96         // desired chunk count (768 blocks = 3/CU, LDS-limited)

// ---- block reduction helpers (256 threads = 4 waves of 64) ----
__device__ inline float blockReduceSum(float v, volatile float* sbuf) {
#pragma unroll
  for (int off = 32; off >= 1; off >>= 1) v += __shfl_xor(v, off, 64);
  const int lane = threadIdx.x & 63;
  const int wv   = threadIdx.x >> 6;
  __syncthreads();
  if (lane == 0) sbuf[wv] = v;
  __syncthreads();
  return sbuf[0] + sbuf[1] + sbuf[2] + sbuf[3];
}

__device__ inline float blockReduceMax(float v, volatile float* sbuf) {
#pragma unroll
  for (int off = 32; off >= 1; off >>= 1) v = fmaxf(v, __shfl_xor(v, off, 64));
  const int lane = threadIdx.x & 63;
  const int wv   = threadIdx.x >> 6;
  __syncthreads();
  if (lane == 0) sbuf[wv] = v;
  __syncthreads();
  return fmaxf(fmaxf(sbuf[0], sbuf[1]), fmaxf(sbuf[2], sbuf[3]));
}

// ---- K1: sequential-stream segment sum, padded-LDS scatter, partial strips ----
__global__ __launch_bounds__(TPB) void k_segsum2(
    const float* __restrict__ q, const float* __restrict__ k,
    const int* __restrict__ lab, int n, int nchunks,
    float* __restrict__ pq, float* __restrict__ pk, int* __restrict__ gcnt) {
  __shared__ float lq[NCLU * LDP];   // 25872 B; bank = (L + 4*f4 + j) % 32
  __shared__ float lk[NCLU * LDP];
  __shared__ int   lc[NCLU];
  const int tid = threadIdx.x;
  const int slice = blockIdx.x;      // 0..SLICES-1
  const int chunk = blockIdx.y;      // 0..nchunks-1

  for (int i = tid; i < NCLU * LDP; i += TPB) { lq[i] = 0.f; lk[i] = 0.f; }
  for (int i = tid; i < NCLU; i += TPB) lc[i] = 0;
  __syncthreads();

  const int lo = (int)(((long)n * chunk) / nchunks);
  const int hi = (int)(((long)n * (chunk + 1)) / nchunks);
  const int sub = tid >> 3;          // 0..31: sample sub-index
  const int f4  = tid & 7;           // 0..7 : float4 within slice
  const float4* __restrict__ q4 = (const float4*)q;
  const float4* __restrict__ k4 = (const float4*)k;
  const int d4 = slice * 8 + f4;
  const bool count_here = (slice == 0) && (f4 == 0);

  for (int s0 = lo; s0 < hi; s0 += 32) {       // 32 sequential samples / block-iter
    const int s = s0 + sub;
    if (s < hi) {
      const int L = lab[s];
      const float4 vq = q4[(long)s * DV4 + d4];
      const float4 vk = k4[(long)s * DV4 + d4];
      const int base = L * LDP + f4 * 4;
      atomicAdd(&lq[base + 0], vq.x);
      atomicAdd(&lq[base + 1], vq.y);
      atomicAdd(&lq[base + 2], vq.z);
      atomicAdd(&lq[base + 3], vq.w);
      atomicAdd(&lk[base + 0], vk.x);
      atomicAdd(&lk[base + 1], vk.y);
      atomicAdd(&lk[base + 2], vk.z);
      atomicAdd(&lk[base + 3], vk.w);
      if (count_here) atomicAdd(&lc[L], 1);
    }
  }
  __syncthreads();

  // Flush to private partial strip (non-atomic, coalesced, pad stripped).
  const long strip = ((long)(slice * nchunks + chunk)) * (NCLU * DPS);
  for (int i = tid; i < NCLU * DPS; i += TPB) {
    const int c = i >> 5, dps = i & 31;
    pq[strip + i] = lq[c * LDP + dps];
    pk[strip + i] = lk[c * LDP + dps];
  }
  if (slice == 0)
    for (int i = tid; i < NCLU; i += TPB)
      if (lc[i]) atomicAdd(&gcnt[i], lc[i]);
}

// ---- K2: reduce partials + normalize; transposed copy + d_k ----
__global__ __launch_bounds__(TPB) void k_centers2(
    const float* __restrict__ pq, const float* __restrict__ pk, int nchunks,
    const int* __restrict__ gcnt,
    float* __restrict__ qc, float* __restrict__ kc,
    float* __restrict__ qcT, float* __restrict__ dk) {
  __shared__ float sbuf[4];
  const int c = blockIdx.x, t = threadIdx.x;   // t indexes dim (DIM == TPB)
  const int slice = t >> 5, dps = t & 31;
  float sq = 0.f, sk = 0.f;
  for (int ch = 0; ch < nchunks; ++ch) {
    const long idx = ((long)(slice * nchunks + ch) * NCLU + c) * DPS + dps;
    sq += pq[idx];
    sk += pk[idx];
  }
  const float denom = fmaxf((float)gcnt[c], EPSV);
  sq /= denom; sk /= denom;
  const float nq = blockReduceSum(sq * sq, sbuf);
  const float nk = blockReduceSum(sk * sk, sbuf);
  const float qv = sq / fmaxf(sqrtf(nq), EPSV);
  const float kv = sk / fmaxf(sqrtf(nk), EPSV);
  qc[c * DIM + t] = qv;
  kc[c * DIM + t] = kv;
  qcT[t * NCLU + c] = qv;
  const float dot = blockReduceSum(qv * kv, sbuf);
  if (t == 0) dk[c] = dot / TEMPERATURE;
}

// ---- K3: per-row similarity + masked logsumexp -> row loss ----
__global__ __launch_bounds__(TPB) void k_rowloss(
    const float* __restrict__ qc, const float* __restrict__ qcT,
    const float* __restrict__ dk, const int* __restrict__ gcnt,
    float* __restrict__ rowloss) {
  __shared__ float qrow[DIM];
  __shared__ float sbuf[4];
  const int c = blockIdx.x, t = threadIdx.x;
  qrow[t] = qc[c * DIM + t];
  __syncthreads();

  float v = -INFINITY;
  if (t < NCLU) {
    float dot = 0.f;
#pragma unroll 8
    for (int d = 0; d < DIM; ++d) dot += qrow[d] * qcT[d * NCLU + t];
    v = dot * (1.0f / TEMPERATURE);       // /0.5 == *2.0, exact
    if (t == c) v = dk[c];                // diag <- d_k (already /T)
    if (gcnt[t] == 0) v = -10.f;          // column mask AFTER diag set
  }
  const float m    = blockReduceMax(v, sbuf);
  const float e    = (t < NCLU) ? expf(v - m) : 0.f;
  const float ssum = blockReduceSum(e, sbuf);
  if (t == 0) {
    float loss = 0.f;
    if (gcnt[c] != 0) loss = -dk[c] + m + logf(ssum);
    rowloss[c] = loss;
  }
}

// ---- K4: final scalar ----
__global__ __launch_bounds__(TPB) void k_final(
    const float* __restrict__ rowloss, const int* __restrict__ gcnt,
    float* __restrict__ out) {
  __shared__ float sbuf[4];
  const int t = threadIdx.x;
  const float ls = (t < NCLU) ? rowloss[t] : 0.f;
  const float nz = (t < NCLU && gcnt[t] == 0) ? 1.f : 0.f;
  const float total = blockReduceSum(ls, sbuf);
  const float nzero = blockReduceSum(nz, sbuf);
  if (t == 0) out[0] = total / ((float)NCLU - nzero);
}

extern "C" void kernel_launch(void* const* d_in, const int* in_sizes, int n_in,
                              void* d_out, int out_size, void* d_ws, size_t ws_size,
                              hipStream_t stream) {
  const float* q  = (const float*)d_in[0];
  const float* k  = (const float*)d_in[1];
  const int* lab  = (const int*)d_in[2];
  const int n = in_sizes[0] / DIM;

  // Fixed-size region first, runtime-sized partial strips after.
  int*   gcnt    = (int*)d_ws;                    // NCLU
  float* qc      = (float*)(gcnt + NCLU);         // NCLU*DIM
  float* kc      = qc + NCLU * DIM;               // NCLU*DIM
  float* qcT     = kc + NCLU * DIM;               // DIM*NCLU
  float* dk      = qcT + DIM * NCLU;              // NCLU
  float* rowloss = dk + NCLU;                     // NCLU
  float* partials = rowloss + NCLU;

  const size_t misc_bytes = (size_t)((char*)partials - (char*)d_ws);
  const size_t per_chunk = (size_t)SLICES * NCLU * DPS * sizeof(float) * 2;
  int nchunks = (ws_size > misc_bytes) ? (int)((ws_size - misc_bytes) / per_chunk) : 1;
  if (nchunks > MAXCH) nchunks = MAXCH;
  if (nchunks < 1) nchunks = 1;
  float* pq = partials;                           // SLICES*nchunks*NCLU*DPS
  float* pk = pq + (size_t)SLICES * nchunks * NCLU * DPS;

  hipMemsetAsync(gcnt, 0, NCLU * sizeof(int), stream);

  dim3 g1(SLICES, nchunks);
  k_segsum2 <<<g1,   TPB, 0, stream>>>(q, k, lab, n, nchunks, pq, pk, gcnt);
  k_centers2<<<NCLU, TPB, 0, stream>>>(pq, pk, nchunks, gcnt, qc, kc, qcT, dk);
  k_rowloss <<<NCLU, TPB, 0, stream>>>(qc, qcT, dk, gcnt, rowloss);
  k_final   <<<1,    TPB, 0, stream>>>(rowloss, gcnt, (float*)d_out);
}